// Round 1
// baseline (196.804 us; speedup 1.0000x reference)
//
#include <hip/hip_runtime.h>
#include <hip/hip_bf16.h>

typedef __attribute__((ext_vector_type(8))) short bf16x8;
typedef __attribute__((ext_vector_type(4))) float f32x4;

#define NB 32
#define NS 512
#define ND 1024

// ws layout:
//   float  inv_norm[NB*NS]   @ 0       (65536 B)
//   ushort a_n[NB*ND]        @ 65536   (65536 B)

__device__ __forceinline__ unsigned short f2bf(float f) {
  unsigned int u = __float_as_uint(f);
  u = (u + 0x7FFFu + ((u >> 16) & 1u)) >> 16;  // RNE: truncation bias would be ~2.5e-3
  return (unsigned short)u;
}

// One wave per embedding row: inv L2 norm.
__global__ void enorm_kernel(const float* __restrict__ emb,
                             float* __restrict__ inv_norm) {
  int wave = threadIdx.x >> 6;
  int lane = threadIdx.x & 63;
  int row  = blockIdx.x * 4 + wave;  // 0..16383
  const float4* p = (const float4*)(emb + (size_t)row * ND);
  float s = 0.f;
#pragma unroll
  for (int j = 0; j < 4; ++j) {
    float4 v = p[lane + 64 * j];
    s += v.x * v.x + v.y * v.y + v.z * v.z + v.w * v.w;
  }
#pragma unroll
  for (int off = 32; off >= 1; off >>= 1) s += __shfl_down(s, off);
  if (lane == 0) inv_norm[row] = (s > 0.f) ? (1.f / sqrtf(s)) : 0.f;
}

// One block per batch: normalized aspect -> bf16.
__global__ void anorm_kernel(const float* __restrict__ aspect,
                             unsigned short* __restrict__ a_n) {
  int b = blockIdx.x;
  int t = threadIdx.x;
  const float4* p = (const float4*)(aspect + (size_t)b * ND);
  float4 v = p[t];
  float s = v.x * v.x + v.y * v.y + v.z * v.z + v.w * v.w;
#pragma unroll
  for (int off = 32; off >= 1; off >>= 1) s += __shfl_down(s, off);
  __shared__ float red[4];
  if ((t & 63) == 0) red[t >> 6] = s;
  __syncthreads();
  float tot = red[0] + red[1] + red[2] + red[3];
  float inv = (tot > 0.f) ? (1.f / sqrtf(tot)) : 0.f;
  ushort4 u;
  u.x = f2bf(v.x * inv); u.y = f2bf(v.y * inv);
  u.z = f2bf(v.z * inv); u.w = f2bf(v.w * inv);
  ((ushort4*)(a_n + (size_t)b * ND))[t] = u;
}

// 128x128 C-tile MFMA GEMM vs circulant B.
// B[k][n] = a_n[(k - n) mod 1024]; b_frag read from 8 shift-copies in LDS.
__global__ __launch_bounds__(256)
void corr_gemm_kernel(const float* __restrict__ emb,
                      const float* __restrict__ inv_norm,
                      const unsigned short* __restrict__ a_n,
                      float* __restrict__ out) {
  __shared__ unsigned short copies[8][2056];  // copy_p[x] = a_n[(x+p)&1023], pad 2056 to spread banks
  __shared__ unsigned short Atile[128][40];   // 80B row stride: 16B-aligned b128 frags

  const int nt = blockIdx.x, mt = blockIdx.y, b = blockIdx.z;
  const int n0 = nt * 128, m0 = mt * 128;
  const int t = threadIdx.x;

  // ---- stage 8 shifted bf16 copies of a_n (once per block) ----
  {
    const unsigned short* an = a_n + (size_t)b * ND;
    int p  = t & 7;
    int x0 = (t >> 3) * 64;  // 0..1984
#pragma unroll
    for (int j = 0; j < 64; j += 4) {
      ushort4 u;
      u.x = an[(x0 + j + 0 + p) & 1023];
      u.y = an[(x0 + j + 1 + p) & 1023];
      u.z = an[(x0 + j + 2 + p) & 1023];
      u.w = an[(x0 + j + 3 + p) & 1023];
      *(ushort4*)&copies[p][x0 + j] = u;
    }
  }

  // per-thread A-staging constants: 4 float4 tasks per K-iter
  const int ar = t >> 3;        // row 0..31 (+32w)
  const int ac = (t & 7) * 4;   // float col 0..28
  float invn[4];
#pragma unroll
  for (int w = 0; w < 4; ++w)
    invn[w] = inv_norm[b * NS + m0 + ar + 32 * w];

  const int lane = t & 63;
  const int wv = t >> 6;
  const int wm = wv >> 1, wn = wv & 1;  // 2x2 waves over 128x128
  const int q = lane >> 4, l16 = lane & 15;

  f32x4 acc[4][4];
#pragma unroll
  for (int i = 0; i < 4; ++i)
#pragma unroll
    for (int j = 0; j < 4; ++j)
      acc[i][j] = (f32x4){0.f, 0.f, 0.f, 0.f};

  const float* embB = emb + ((size_t)b * NS + m0) * ND;

  for (int k0 = 0; k0 < ND; k0 += 32) {
    __syncthreads();
    // ---- stage A tile: normalize fp32 -> bf16 ----
#pragma unroll
    for (int w = 0; w < 4; ++w) {
      int r = ar + 32 * w;
      float4 v = *(const float4*)(embB + (size_t)r * ND + k0 + ac);
      float in = invn[w];
      ushort4 u;
      u.x = f2bf(v.x * in); u.y = f2bf(v.y * in);
      u.z = f2bf(v.z * in); u.w = f2bf(v.w * in);
      *(ushort4*)&Atile[r][ac] = u;
    }
    __syncthreads();

    // ---- fragments ----
    bf16x8 af[4], bfr[4];
#pragma unroll
    for (int r = 0; r < 4; ++r) {
      int m = wm * 64 + r * 16 + l16;
      af[r] = *(const bf16x8*)&Atile[m][q * 8];
    }
#pragma unroll
    for (int r = 0; r < 4; ++r) {
      int ng = n0 + wn * 64 + r * 16 + l16;
      int e0 = k0 + 8 * q - ng + 1024;  // in [1, 2040]
      int p  = e0 & 7;
      bfr[r] = *(const bf16x8*)&copies[p][e0 - p];  // 16B-aligned contiguous window
    }
#pragma unroll
    for (int i = 0; i < 4; ++i)
#pragma unroll
      for (int j = 0; j < 4; ++j)
        acc[i][j] = __builtin_amdgcn_mfma_f32_16x16x32_bf16(af[i], bfr[j], acc[i][j], 0, 0, 0);
  }

  // ---- epilogue: C/D layout col=lane&15, row=(lane>>4)*4+reg ----
  float* outB = out + ((size_t)b * NS + m0) * ND + n0;
#pragma unroll
  for (int i = 0; i < 4; ++i) {
#pragma unroll
    for (int rg = 0; rg < 4; ++rg) {
      int s = wm * 64 + i * 16 + q * 4 + rg;
      float* orow = outB + (size_t)s * ND + wn * 64 + l16;
#pragma unroll
      for (int j = 0; j < 4; ++j)
        orow[j * 16] = acc[i][j][rg];
    }
  }
}

extern "C" void kernel_launch(void* const* d_in, const int* in_sizes, int n_in,
                              void* d_out, int out_size, void* d_ws, size_t ws_size,
                              hipStream_t stream) {
  const float* emb    = (const float*)d_in[0];
  const float* aspect = (const float*)d_in[1];
  float* out = (float*)d_out;

  float* inv_norm      = (float*)d_ws;
  unsigned short* a_n  = (unsigned short*)((char*)d_ws + 65536);

  enorm_kernel<<<4096, 256, 0, stream>>>(emb, inv_norm);
  anorm_kernel<<<NB, 256, 0, stream>>>(aspect, a_n);
  corr_gemm_kernel<<<dim3(8, 4, NB), 256, 0, stream>>>(emb, inv_norm, a_n, out);
}

// Round 2
// 160.962 us; speedup vs baseline: 1.2227x; 1.2227x over previous
//
#include <hip/hip_runtime.h>
#include <hip/hip_bf16.h>

typedef __attribute__((ext_vector_type(8))) short bf16x8;
typedef __attribute__((ext_vector_type(4))) float f32x4;

#define NB 32
#define NS 512
#define ND 1024

__device__ __forceinline__ unsigned short f2bf(float f) {
  unsigned int u = __float_as_uint(f);
  u = (u + 0x7FFFu + ((u >> 16) & 1u)) >> 16;  // RNE: truncation bias would be ~2.5e-3
  return (unsigned short)u;
}

// ---------- shared small kernel: normalized aspect -> bf16 ----------
__global__ void anorm_kernel(const float* __restrict__ aspect,
                             unsigned short* __restrict__ a_n) {
  int b = blockIdx.x;
  int t = threadIdx.x;
  const float4* p = (const float4*)(aspect + (size_t)b * ND);
  float4 v = p[t];
  float s = v.x * v.x + v.y * v.y + v.z * v.z + v.w * v.w;
#pragma unroll
  for (int off = 32; off >= 1; off >>= 1) s += __shfl_down(s, off);
  __shared__ float red[4];
  if ((t & 63) == 0) red[t >> 6] = s;
  __syncthreads();
  float tot = red[0] + red[1] + red[2] + red[3];
  float inv = (tot > 0.f) ? (1.f / sqrtf(tot)) : 0.f;
  ushort4 u;
  u.x = f2bf(v.x * inv); u.y = f2bf(v.y * inv);
  u.z = f2bf(v.z * inv); u.w = f2bf(v.w * inv);
  ((ushort4*)(a_n + (size_t)b * ND))[t] = u;
}

// ---------- NEW: precompute normalized embeddings as bf16 (one wave/row) ----------
__global__ __launch_bounds__(256)
void enormbf_kernel(const float* __restrict__ emb,
                    unsigned short* __restrict__ eN) {
  int wave = threadIdx.x >> 6, lane = threadIdx.x & 63;
  size_t row = (size_t)blockIdx.x * 4 + wave;  // 0..16383
  const float4* p = (const float4*)(emb + row * ND);
  float4 v[4];
  float s = 0.f;
#pragma unroll
  for (int j = 0; j < 4; ++j) {
    v[j] = p[lane + 64 * j];
    s += v[j].x * v[j].x + v[j].y * v[j].y + v[j].z * v[j].z + v[j].w * v[j].w;
  }
#pragma unroll
  for (int off = 32; off >= 1; off >>= 1) s += __shfl_xor(s, off);
  float inv = (s > 0.f) ? (1.f / sqrtf(s)) : 0.f;
  ushort4* o = (ushort4*)(eN + row * ND);
#pragma unroll
  for (int j = 0; j < 4; ++j) {
    ushort4 u;
    u.x = f2bf(v[j].x * inv); u.y = f2bf(v[j].y * inv);
    u.z = f2bf(v[j].z * inv); u.w = f2bf(v[j].w * inv);
    o[lane + 64 * j] = u;
  }
}

// ---------- NEW GEMM: bf16 A via global_load_lds, BK=64, XOR-swizzled A slots ----------
__global__ __launch_bounds__(256)
void corr_gemm2_kernel(const unsigned short* __restrict__ eN,
                       const unsigned short* __restrict__ a_n,
                       float* __restrict__ out) {
  __shared__ unsigned short copies[8][2056];  // copy_p[x] = a_n[(x+p)&1023]
  __shared__ unsigned short Atile[128 * 64];  // row stride 64 elem; slot s holds chunk c = s ^ (row&7)

  const int nt = blockIdx.x, mt = blockIdx.y, b = blockIdx.z;
  const int n0 = nt * 128, m0 = mt * 128;
  const int t = threadIdx.x;

  // stage 8 shifted bf16 copies of a_n (once per block)
  {
    const unsigned short* an = a_n + (size_t)b * ND;
    int p = t & 7;
    int x0 = (t >> 3) * 64;  // 0..1984
#pragma unroll
    for (int j = 0; j < 64; j += 4) {
      ushort4 u;
      u.x = an[(x0 + j + 0 + p) & 1023];
      u.y = an[(x0 + j + 1 + p) & 1023];
      u.z = an[(x0 + j + 2 + p) & 1023];
      u.w = an[(x0 + j + 3 + p) & 1023];
      *(ushort4*)&copies[p][x0 + j] = u;
    }
  }

  const int lane = t & 63, wv = t >> 6;
  const int wm = wv >> 1, wn = wv & 1;  // 2x2 waves over 128x128
  const int q = lane >> 4, l16 = lane & 15;

  // A staging: pass j covers rows j*32 + wv*8 + (lane>>3); chunk c = (lane&7)^(lane>>3)
  // -> LDS dst = wave-uniform base + lane*16 (global_load_lds constraint), swizzle on SOURCE addr
  const int srow = wv * 8 + (lane >> 3);
  const int sc = (lane & 7) ^ (lane >> 3);
  const unsigned short* gsrc = eN + ((size_t)b * NS + m0 + srow) * ND + sc * 8;
  char* ldsA = (char*)Atile;
  const int ldst0 = wv * 1024 + lane * 16;

  f32x4 acc[4][4];
#pragma unroll
  for (int i = 0; i < 4; ++i)
#pragma unroll
    for (int j = 0; j < 4; ++j)
      acc[i][j] = (f32x4){0.f, 0.f, 0.f, 0.f};

  for (int k0 = 0; k0 < ND; k0 += 64) {
    __syncthreads();
#pragma unroll
    for (int j = 0; j < 4; ++j) {
      __builtin_amdgcn_global_load_lds(
          (const __attribute__((address_space(1))) void*)(gsrc + (size_t)j * 32 * ND + k0),
          (__attribute__((address_space(3))) void*)(ldsA + ldst0 + j * 4096),
          16, 0, 0);
    }
    __syncthreads();

#pragma unroll
    for (int kk = 0; kk < 2; ++kk) {
      bf16x8 af[4], bfr[4];
#pragma unroll
      for (int r = 0; r < 4; ++r) {
        int m = wm * 64 + r * 16 + l16;
        int c = kk * 4 + q;
        int s = c ^ (m & 7);
        af[r] = *(const bf16x8*)&Atile[m * 64 + s * 8];

        int ng = n0 + wn * 64 + r * 16 + l16;
        int e0 = k0 + kk * 32 + 8 * q - ng + 1024;  // in [1, 2040]
        int p = e0 & 7;
        bfr[r] = *(const bf16x8*)&copies[p][e0 - p];
      }
#pragma unroll
      for (int i = 0; i < 4; ++i)
#pragma unroll
        for (int j2 = 0; j2 < 4; ++j2)
          acc[i][j2] = __builtin_amdgcn_mfma_f32_16x16x32_bf16(af[i], bfr[j2], acc[i][j2], 0, 0, 0);
    }
  }

  // epilogue: C/D layout col=lane&15, row=(lane>>4)*4+reg
  float* outB = out + ((size_t)b * NS + m0) * ND + n0;
#pragma unroll
  for (int i = 0; i < 4; ++i) {
#pragma unroll
    for (int rg = 0; rg < 4; ++rg) {
      int s = wm * 64 + i * 16 + q * 4 + rg;
      float* orow = outB + (size_t)s * ND + wn * 64 + l16;
#pragma unroll
      for (int j = 0; j < 4; ++j)
        orow[j * 16] = acc[i][j][rg];
    }
  }
}

// ---------- fallback path (round-1 kernels) in case ws is small ----------
__global__ void enorm_kernel(const float* __restrict__ emb,
                             float* __restrict__ inv_norm) {
  int wave = threadIdx.x >> 6;
  int lane = threadIdx.x & 63;
  int row = blockIdx.x * 4 + wave;
  const float4* p = (const float4*)(emb + (size_t)row * ND);
  float s = 0.f;
#pragma unroll
  for (int j = 0; j < 4; ++j) {
    float4 v = p[lane + 64 * j];
    s += v.x * v.x + v.y * v.y + v.z * v.z + v.w * v.w;
  }
#pragma unroll
  for (int off = 32; off >= 1; off >>= 1) s += __shfl_down(s, off);
  if (lane == 0) inv_norm[row] = (s > 0.f) ? (1.f / sqrtf(s)) : 0.f;
}

__global__ __launch_bounds__(256)
void corr_gemm_kernel(const float* __restrict__ emb,
                      const float* __restrict__ inv_norm,
                      const unsigned short* __restrict__ a_n,
                      float* __restrict__ out) {
  __shared__ unsigned short copies[8][2056];
  __shared__ unsigned short Atile[128][40];

  const int nt = blockIdx.x, mt = blockIdx.y, b = blockIdx.z;
  const int n0 = nt * 128, m0 = mt * 128;
  const int t = threadIdx.x;

  {
    const unsigned short* an = a_n + (size_t)b * ND;
    int p = t & 7;
    int x0 = (t >> 3) * 64;
#pragma unroll
    for (int j = 0; j < 64; j += 4) {
      ushort4 u;
      u.x = an[(x0 + j + 0 + p) & 1023];
      u.y = an[(x0 + j + 1 + p) & 1023];
      u.z = an[(x0 + j + 2 + p) & 1023];
      u.w = an[(x0 + j + 3 + p) & 1023];
      *(ushort4*)&copies[p][x0 + j] = u;
    }
  }

  const int ar = t >> 3;
  const int ac = (t & 7) * 4;
  float invn[4];
#pragma unroll
  for (int w = 0; w < 4; ++w)
    invn[w] = inv_norm[b * NS + m0 + ar + 32 * w];

  const int lane = t & 63;
  const int wv = t >> 6;
  const int wm = wv >> 1, wn = wv & 1;
  const int q = lane >> 4, l16 = lane & 15;

  f32x4 acc[4][4];
#pragma unroll
  for (int i = 0; i < 4; ++i)
#pragma unroll
    for (int j = 0; j < 4; ++j)
      acc[i][j] = (f32x4){0.f, 0.f, 0.f, 0.f};

  const float* embB = emb + ((size_t)b * NS + m0) * ND;

  for (int k0 = 0; k0 < ND; k0 += 32) {
    __syncthreads();
#pragma unroll
    for (int w = 0; w < 4; ++w) {
      int r = ar + 32 * w;
      float4 v = *(const float4*)(embB + (size_t)r * ND + k0 + ac);
      float in = invn[w];
      ushort4 u;
      u.x = f2bf(v.x * in); u.y = f2bf(v.y * in);
      u.z = f2bf(v.z * in); u.w = f2bf(v.w * in);
      *(ushort4*)&Atile[r][ac] = u;
    }
    __syncthreads();

    bf16x8 af[4], bfr[4];
#pragma unroll
    for (int r = 0; r < 4; ++r) {
      int m = wm * 64 + r * 16 + l16;
      af[r] = *(const bf16x8*)&Atile[m][q * 8];
    }
#pragma unroll
    for (int r = 0; r < 4; ++r) {
      int ng = n0 + wn * 64 + r * 16 + l16;
      int e0 = k0 + 8 * q - ng + 1024;
      int p = e0 & 7;
      bfr[r] = *(const bf16x8*)&copies[p][e0 - p];
    }
#pragma unroll
    for (int i = 0; i < 4; ++i)
#pragma unroll
      for (int j = 0; j < 4; ++j)
        acc[i][j] = __builtin_amdgcn_mfma_f32_16x16x32_bf16(af[i], bfr[j], acc[i][j], 0, 0, 0);
  }

  float* outB = out + ((size_t)b * NS + m0) * ND + n0;
#pragma unroll
  for (int i = 0; i < 4; ++i) {
#pragma unroll
    for (int rg = 0; rg < 4; ++rg) {
      int s = wm * 64 + i * 16 + q * 4 + rg;
      float* orow = outB + (size_t)s * ND + wn * 64 + l16;
#pragma unroll
      for (int j = 0; j < 4; ++j)
        orow[j * 16] = acc[i][j][rg];
    }
  }
}

extern "C" void kernel_launch(void* const* d_in, const int* in_sizes, int n_in,
                              void* d_out, int out_size, void* d_ws, size_t ws_size,
                              hipStream_t stream) {
  const float* emb = (const float*)d_in[0];
  const float* aspect = (const float*)d_in[1];
  float* out = (float*)d_out;

  const size_t need = 65536 + (size_t)NB * NS * ND * 2;  // a_n + eN(bf16)

  if (ws_size >= need) {
    unsigned short* a_n = (unsigned short*)d_ws;
    unsigned short* eN = (unsigned short*)((char*)d_ws + 65536);
    anorm_kernel<<<NB, 256, 0, stream>>>(aspect, a_n);
    enormbf_kernel<<<4096, 256, 0, stream>>>(emb, eN);
    corr_gemm2_kernel<<<dim3(8, 4, NB), 256, 0, stream>>>(eN, a_n, out);
  } else {
    float* inv_norm = (float*)d_ws;
    unsigned short* a_n = (unsigned short*)((char*)d_ws + 65536);
    enorm_kernel<<<4096, 256, 0, stream>>>(emb, inv_norm);
    anorm_kernel<<<NB, 256, 0, stream>>>(aspect, a_n);
    corr_gemm_kernel<<<dim3(8, 4, NB), 256, 0, stream>>>(emb, inv_norm, a_n, out);
  }
}

// Round 3
// 143.197 us; speedup vs baseline: 1.3744x; 1.1241x over previous
//
#include <hip/hip_runtime.h>
#include <hip/hip_bf16.h>

typedef __attribute__((ext_vector_type(8))) short bf16x8;
typedef __attribute__((ext_vector_type(4))) float f32x4;

#define NB 32
#define NS 512
#define ND 1024

__device__ __forceinline__ unsigned short f2bf(float f) {
  unsigned int u = __float_as_uint(f);
  u = (u + 0x7FFFu + ((u >> 16) & 1u)) >> 16;  // RNE: truncation bias would be ~2.5e-3
  return (unsigned short)u;
}

// ---------- normalized aspect -> bf16 ----------
__global__ void anorm_kernel(const float* __restrict__ aspect,
                             unsigned short* __restrict__ a_n) {
  int b = blockIdx.x;
  int t = threadIdx.x;
  const float4* p = (const float4*)(aspect + (size_t)b * ND);
  float4 v = p[t];
  float s = v.x * v.x + v.y * v.y + v.z * v.z + v.w * v.w;
#pragma unroll
  for (int off = 32; off >= 1; off >>= 1) s += __shfl_down(s, off);
  __shared__ float red[4];
  if ((t & 63) == 0) red[t >> 6] = s;
  __syncthreads();
  float tot = red[0] + red[1] + red[2] + red[3];
  float inv = (tot > 0.f) ? (1.f / sqrtf(tot)) : 0.f;
  ushort4 u;
  u.x = f2bf(v.x * inv); u.y = f2bf(v.y * inv);
  u.z = f2bf(v.z * inv); u.w = f2bf(v.w * inv);
  ((ushort4*)(a_n + (size_t)b * ND))[t] = u;
}

// ---------- precompute normalized embeddings as bf16 (one wave/row) ----------
__global__ __launch_bounds__(256)
void enormbf_kernel(const float* __restrict__ emb,
                    unsigned short* __restrict__ eN) {
  int wave = threadIdx.x >> 6, lane = threadIdx.x & 63;
  size_t row = (size_t)blockIdx.x * 4 + wave;  // 0..16383
  const float4* p = (const float4*)(emb + row * ND);
  float4 v[4];
  float s = 0.f;
#pragma unroll
  for (int j = 0; j < 4; ++j) {
    v[j] = p[lane + 64 * j];
    s += v[j].x * v[j].x + v[j].y * v[j].y + v[j].z * v[j].z + v[j].w * v[j].w;
  }
#pragma unroll
  for (int off = 32; off >= 1; off >>= 1) s += __shfl_xor(s, off);
  float inv = (s > 0.f) ? (1.f / sqrtf(s)) : 0.f;
  ushort4* o = (ushort4*)(eN + row * ND);
#pragma unroll
  for (int j = 0; j < 4; ++j) {
    ushort4 u;
    u.x = f2bf(v[j].x * inv); u.y = f2bf(v[j].y * inv);
    u.z = f2bf(v[j].z * inv); u.w = f2bf(v[j].w * inv);
    o[lane + 64 * j] = u;
  }
}

// ---------- GEMM v3: windowed circulant copies (34.9 KB LDS -> 4 blk/CU,
// perfectly-resident 1024-block grid) + XCD-aware grid (b,mt,nt) ----------
__global__ __launch_bounds__(256, 4)
void corr_gemm3_kernel(const unsigned short* __restrict__ eN,
                       const unsigned short* __restrict__ a_n,
                       float* __restrict__ out) {
  // copies[p][x] = a[(x + (896 - n0) + p) & 1023]; block only needs idx in [0,1151]
  __shared__ unsigned short copies[8][1160];  // stride 1160 (2320B = 580 dw = +4 banks stagger)
  __shared__ unsigned short Atile[128 * 64];  // slot s holds chunk c = s ^ (row&7)

  const int b = blockIdx.x, mt = blockIdx.y, nt = blockIdx.z;
  const int n0 = nt * 128, m0 = mt * 128;
  const int t = threadIdx.x;

  // stage windowed shift-copies (once per block): 8 x 1152 entries
  {
    const unsigned short* an = a_n + (size_t)b * ND;
    int p = t & 7;
    int x0 = (t >> 3) * 36;                 // 32 threads/copy x 36 = 1152
    int base = (896 - n0 + p) & 1023;
#pragma unroll
    for (int j = 0; j < 36; j += 4) {
      ushort4 u;
      u.x = an[(base + x0 + j + 0) & 1023];
      u.y = an[(base + x0 + j + 1) & 1023];
      u.z = an[(base + x0 + j + 2) & 1023];
      u.w = an[(base + x0 + j + 3) & 1023];
      *(ushort4*)&copies[p][x0 + j] = u;
    }
  }

  const int lane = t & 63, wv = t >> 6;
  const int wm = wv >> 1, wn = wv & 1;  // 2x2 waves over 128x128
  const int q = lane >> 4, l16 = lane & 15;

  // A staging (global_load_lds, XOR source swizzle; LDS dst = uniform + lane*16)
  const int srow = wv * 8 + (lane >> 3);
  const int sc = (lane & 7) ^ (lane >> 3);
  const unsigned short* gsrc = eN + ((size_t)b * NS + m0 + srow) * ND + sc * 8;
  char* ldsA = (char*)Atile;
  const int ldst0 = wv * 1024 + lane * 16;

  f32x4 acc[4][4];
#pragma unroll
  for (int i = 0; i < 4; ++i)
#pragma unroll
    for (int j = 0; j < 4; ++j)
      acc[i][j] = (f32x4){0.f, 0.f, 0.f, 0.f};

  for (int k0 = 0; k0 < ND; k0 += 64) {
    __syncthreads();
#pragma unroll
    for (int j = 0; j < 4; ++j) {
      __builtin_amdgcn_global_load_lds(
          (const __attribute__((address_space(1))) void*)(gsrc + (size_t)j * 32 * ND + k0),
          (__attribute__((address_space(3))) void*)(ldsA + ldst0 + j * 4096),
          16, 0, 0);
    }
    __syncthreads();

#pragma unroll
    for (int kk = 0; kk < 2; ++kk) {
      bf16x8 af[4], bfr[4];
#pragma unroll
      for (int r = 0; r < 4; ++r) {
        int m = wm * 64 + r * 16 + l16;
        int c = kk * 4 + q;
        int s = c ^ (m & 7);
        af[r] = *(const bf16x8*)&Atile[m * 64 + s * 8];

        int idx = k0 + kk * 32 + 8 * q + 128 - (wn * 64 + r * 16 + l16);  // in [1,1144]
        int p = idx & 7;
        bfr[r] = *(const bf16x8*)&copies[p][idx - p];  // 16B-aligned window
      }
#pragma unroll
      for (int i = 0; i < 4; ++i)
#pragma unroll
        for (int j2 = 0; j2 < 4; ++j2)
          acc[i][j2] = __builtin_amdgcn_mfma_f32_16x16x32_bf16(af[i], bfr[j2], acc[i][j2], 0, 0, 0);
    }
  }

  // epilogue: C/D layout col=lane&15, row=(lane>>4)*4+reg
  float* outB = out + ((size_t)b * NS + m0) * ND + n0;
#pragma unroll
  for (int i = 0; i < 4; ++i) {
#pragma unroll
    for (int rg = 0; rg < 4; ++rg) {
      int s = wm * 64 + i * 16 + q * 4 + rg;
      float* orow = outB + (size_t)s * ND + wn * 64 + l16;
#pragma unroll
      for (int j = 0; j < 4; ++j)
        orow[j * 16] = acc[i][j][rg];
    }
  }
}

// ---------- fallback path (round-1 kernels) in case ws is small ----------
__global__ void enorm_kernel(const float* __restrict__ emb,
                             float* __restrict__ inv_norm) {
  int wave = threadIdx.x >> 6;
  int lane = threadIdx.x & 63;
  int row = blockIdx.x * 4 + wave;
  const float4* p = (const float4*)(emb + (size_t)row * ND);
  float s = 0.f;
#pragma unroll
  for (int j = 0; j < 4; ++j) {
    float4 v = p[lane + 64 * j];
    s += v.x * v.x + v.y * v.y + v.z * v.z + v.w * v.w;
  }
#pragma unroll
  for (int off = 32; off >= 1; off >>= 1) s += __shfl_down(s, off);
  if (lane == 0) inv_norm[row] = (s > 0.f) ? (1.f / sqrtf(s)) : 0.f;
}

__global__ __launch_bounds__(256)
void corr_gemm_kernel(const float* __restrict__ emb,
                      const float* __restrict__ inv_norm,
                      const unsigned short* __restrict__ a_n,
                      float* __restrict__ out) {
  __shared__ unsigned short copies[8][2056];
  __shared__ unsigned short Atile[128][40];

  const int nt = blockIdx.x, mt = blockIdx.y, b = blockIdx.z;
  const int n0 = nt * 128, m0 = mt * 128;
  const int t = threadIdx.x;

  {
    const unsigned short* an = a_n + (size_t)b * ND;
    int p = t & 7;
    int x0 = (t >> 3) * 64;
#pragma unroll
    for (int j = 0; j < 64; j += 4) {
      ushort4 u;
      u.x = an[(x0 + j + 0 + p) & 1023];
      u.y = an[(x0 + j + 1 + p) & 1023];
      u.z = an[(x0 + j + 2 + p) & 1023];
      u.w = an[(x0 + j + 3 + p) & 1023];
      *(ushort4*)&copies[p][x0 + j] = u;
    }
  }

  const int ar = t >> 3;
  const int ac = (t & 7) * 4;
  float invn[4];
#pragma unroll
  for (int w = 0; w < 4; ++w)
    invn[w] = inv_norm[b * NS + m0 + ar + 32 * w];

  const int lane = t & 63;
  const int wv = t >> 6;
  const int wm = wv >> 1, wn = wv & 1;
  const int q = lane >> 4, l16 = lane & 15;

  f32x4 acc[4][4];
#pragma unroll
  for (int i = 0; i < 4; ++i)
#pragma unroll
    for (int j = 0; j < 4; ++j)
      acc[i][j] = (f32x4){0.f, 0.f, 0.f, 0.f};

  const float* embB = emb + ((size_t)b * NS + m0) * ND;

  for (int k0 = 0; k0 < ND; k0 += 32) {
    __syncthreads();
#pragma unroll
    for (int w = 0; w < 4; ++w) {
      int r = ar + 32 * w;
      float4 v = *(const float4*)(embB + (size_t)r * ND + k0 + ac);
      float in = invn[w];
      ushort4 u;
      u.x = f2bf(v.x * in); u.y = f2bf(v.y * in);
      u.z = f2bf(v.z * in); u.w = f2bf(v.w * in);
      *(ushort4*)&Atile[r][ac] = u;
    }
    __syncthreads();

    bf16x8 af[4], bfr[4];
#pragma unroll
    for (int r = 0; r < 4; ++r) {
      int m = wm * 64 + r * 16 + l16;
      af[r] = *(const bf16x8*)&Atile[m][q * 8];
    }
#pragma unroll
    for (int r = 0; r < 4; ++r) {
      int ng = n0 + wn * 64 + r * 16 + l16;
      int e0 = k0 + 8 * q - ng + 1024;
      int p = e0 & 7;
      bfr[r] = *(const bf16x8*)&copies[p][e0 - p];
    }
#pragma unroll
    for (int i = 0; i < 4; ++i)
#pragma unroll
      for (int j = 0; j < 4; ++j)
        acc[i][j] = __builtin_amdgcn_mfma_f32_16x16x32_bf16(af[i], bfr[j], acc[i][j], 0, 0, 0);
  }

  float* outB = out + ((size_t)b * NS + m0) * ND + n0;
#pragma unroll
  for (int i = 0; i < 4; ++i) {
#pragma unroll
    for (int rg = 0; rg < 4; ++rg) {
      int s = wm * 64 + i * 16 + q * 4 + rg;
      float* orow = outB + (size_t)s * ND + wn * 64 + l16;
#pragma unroll
      for (int j = 0; j < 4; ++j)
        orow[j * 16] = acc[i][j][rg];
    }
  }
}

extern "C" void kernel_launch(void* const* d_in, const int* in_sizes, int n_in,
                              void* d_out, int out_size, void* d_ws, size_t ws_size,
                              hipStream_t stream) {
  const float* emb = (const float*)d_in[0];
  const float* aspect = (const float*)d_in[1];
  float* out = (float*)d_out;

  const size_t need = 65536 + (size_t)NB * NS * ND * 2;  // a_n + eN(bf16)

  if (ws_size >= need) {
    unsigned short* a_n = (unsigned short*)d_ws;
    unsigned short* eN = (unsigned short*)((char*)d_ws + 65536);
    anorm_kernel<<<NB, 256, 0, stream>>>(aspect, a_n);
    enormbf_kernel<<<4096, 256, 0, stream>>>(emb, eN);
    // grid (b, mt, nt): nt-siblings differ by 128 in flat id -> same XCD -> A-panel L2 reuse
    corr_gemm3_kernel<<<dim3(NB, 4, 8), 256, 0, stream>>>(eN, a_n, out);
  } else {
    float* inv_norm = (float*)d_ws;
    unsigned short* a_n = (unsigned short*)((char*)d_ws + 65536);
    enorm_kernel<<<4096, 256, 0, stream>>>(emb, inv_norm);
    anorm_kernel<<<NB, 256, 0, stream>>>(aspect, a_n);
    corr_gemm_kernel<<<dim3(8, 4, NB), 256, 0, stream>>>(emb, inv_norm, a_n, out);
  }
}